// Round 11
// baseline (488.084 us; speedup 1.0000x reference)
//
#include <hip/hip_runtime.h>

// Problem constants
// N=8, T_y=300, T_x=160, E=256, E/2=128, 3E=768
// d_out: [attn 8*300*160 = 384000][outputs 8*300*256 = 614400][hidden 2048]

typedef _Float16 f16x2 __attribute__((ext_vector_type(2)));
typedef _Float16 f16x8 __attribute__((ext_vector_type(8)));
typedef float f32x4 __attribute__((ext_vector_type(4)));

__device__ __forceinline__ float fexp2(float x) { return __builtin_amdgcn_exp2f(x); }
__device__ __forceinline__ float frcp(float x) { return __builtin_amdgcn_rcpf(x); }
__device__ __forceinline__ float fsig(float x) {
    return frcp(1.0f + fexp2(x * -1.4426950408889634f));
}
__device__ __forceinline__ float ftanh(float x) {
    return 1.0f - 2.0f * frcp(1.0f + fexp2(x * 2.8853900817779268f));
}

// select component s (0..3) of a f32x4 with runtime s — pure cndmask tree
// (rule #20: no runtime array indexing).
__device__ __forceinline__ float pick4(f32x4 v, int s) {
    float ab = (s & 1) ? v[1] : v[0];
    float cd = (s & 1) ? v[3] : v[2];
    return (s & 2) ? cd : ab;
}

// Flags live 128B apart (one per cache line).
#define FLAG(i) ((i) * 32)

// Fresh flag read: agent-scope atomic RMW (add 0) executes at the MALL
// coherence point — can NEVER return a stale XCD-L2 copy (a remote RELEASE
// writes through to MALL but does not invalidate other XCDs' clean lines;
// r8/r10 evidence: plain RELAXED loads woke consumers ~60us late).
__device__ __forceinline__ int flag_rmw_relaxed(int* p) {
    return __hip_atomic_fetch_add(p, 0, __ATOMIC_RELAXED,
                                  __HIP_MEMORY_SCOPE_AGENT);
}
__device__ __forceinline__ void flag_fence_acquire(int* p) {
    (void)__hip_atomic_fetch_add(p, 0, __ATOMIC_ACQUIRE,
                                 __HIP_MEMORY_SCOPE_AGENT);
}

// ---------------------------------------------------------------------------
// Kernel 1 (phase 1): blocks 0..383 repack Whh into MFMA A-fragment order;
// blocks 384..839 run the gi GEMM (bias-folded, scattered). Block 0 zeroes
// the padded flags (visible to mega via the launch boundary).
// Layout verified r2+ (absmax 0.0039).
// ---------------------------------------------------------------------------
__global__ __launch_bounds__(256) void phase1_kernel(
    const float* __restrict__ Whh, unsigned* __restrict__ wd,
    const float* __restrict__ inputs, const float* __restrict__ Wih,
    float* __restrict__ gi, const float* __restrict__ bih,
    const float* __restrict__ bhh, int* flags, int full) {
    if (full && blockIdx.x == 0 && threadIdx.x < 9)
        flags[FLAG(threadIdx.x)] = 0;
    if (blockIdx.x < 384) {
        int gid = blockIdx.x * 256 + threadIdx.x;   // 0..98303 = 192*512
        int i = gid >> 9, t = gid & 511;
        int fi = i >> 2, j = i & 3;
        int g = fi >> 4, m2 = (fi >> 3) & 1, ks = fi & 7;
        int w = t >> 6, l = t & 63;
        int row = 256 * g + 32 * w + 16 * m2 + (l & 15);
        int k = 32 * ks + 8 * (l >> 4) + 2 * j;
        union { unsigned u; f16x2 h; } cv;
        cv.h[0] = (_Float16)Whh[(size_t)row * 256 + k];
        cv.h[1] = (_Float16)Whh[(size_t)row * 256 + k + 1];
        wd[i * 512 + t] = cv.u;
        return;
    }
    int id = blockIdx.x - 384;                   // 0..455 = 12 x 38
    const int n0 = (id % 12) * 64, m0 = (id / 12) * 64;
    __shared__ float Xs[32][65];
    __shared__ float Ws2[32][65];
    const int tid = threadIdx.x;
    const int tx = tid & 15, ty = tid >> 4;
    const int M = 2400, K = 128;
    float acc[4][4] = {};
    for (int k0 = 0; k0 < K; k0 += 32) {
#pragma unroll
        for (int i = 0; i < 8; ++i) {
            int e = tid + i * 256;
            int kk = e & 31, m = e >> 5;
            int row = m0 + m;
            Xs[kk][m] = (row < M) ? inputs[(size_t)row * K + k0 + kk] : 0.0f;
            Ws2[kk][m] = Wih[(size_t)(n0 + m) * K + k0 + kk];
        }
        __syncthreads();
#pragma unroll
        for (int kk = 0; kk < 32; ++kk) {
            float a[4], b[4];
#pragma unroll
            for (int i = 0; i < 4; ++i) a[i] = Xs[kk][ty * 4 + i];
#pragma unroll
            for (int j = 0; j < 4; ++j) b[j] = Ws2[kk][tx * 4 + j];
#pragma unroll
            for (int i = 0; i < 4; ++i)
#pragma unroll
                for (int j = 0; j < 4; ++j) acc[i][j] += a[i] * b[j];
        }
        __syncthreads();
    }
#pragma unroll
    for (int i = 0; i < 4; ++i) {
        int row = m0 + ty * 4 + i;
        if (row >= M) continue;
        int b = row / 300;
        int t = row - b * 300;
#pragma unroll
        for (int j = 0; j < 4; ++j) {
            int col = n0 + tx * 4 + j;
            float val = acc[i][j] + ((col < 512) ? (bih[col] + bhh[col]) : bih[col]);
            gi[(size_t)(t * 8 + b) * 768 + col] = val;
        }
    }
}

// ---------------------------------------------------------------------------
// Kernel B (FALLBACK only): generic f32 tiled GEMM, mode 2 writes f16.
// ---------------------------------------------------------------------------
__global__ __launch_bounds__(256) void gemm_kernel(
    const float* __restrict__ X, const float* __restrict__ Wt,
    float* __restrict__ C, _Float16* __restrict__ C16,
    int M, int N, int K, int mode) {
    __shared__ float Xs[32][65];
    __shared__ float Ws2[32][65];
    const int n0 = blockIdx.x * 64, m0 = blockIdx.y * 64;
    const int tid = threadIdx.x;
    const int tx = tid & 15, ty = tid >> 4;
    float acc[4][4] = {};
    for (int k0 = 0; k0 < K; k0 += 32) {
#pragma unroll
        for (int i = 0; i < 8; ++i) {
            int e = tid + i * 256;
            int kk = e & 31, m = e >> 5;
            int row = m0 + m;
            Xs[kk][m] = (row < M) ? X[(size_t)row * K + k0 + kk] : 0.0f;
            Ws2[kk][m] = Wt[(size_t)(n0 + m) * K + k0 + kk];
        }
        __syncthreads();
#pragma unroll
        for (int kk = 0; kk < 32; ++kk) {
            float a[4], b[4];
#pragma unroll
            for (int i = 0; i < 4; ++i) a[i] = Xs[kk][ty * 4 + i];
#pragma unroll
            for (int j = 0; j < 4; ++j) b[j] = Ws2[kk][tx * 4 + j];
#pragma unroll
            for (int i = 0; i < 4; ++i)
#pragma unroll
                for (int j = 0; j < 4; ++j) acc[i][j] += a[i] * b[j];
        }
        __syncthreads();
    }
#pragma unroll
    for (int i = 0; i < 4; ++i) {
        int row = m0 + ty * 4 + i;
        if (row >= M) continue;
#pragma unroll
        for (int j = 0; j < 4; ++j) {
            int col = n0 + tx * 4 + j;
            if (mode == 2) C16[(size_t)row * N + col] = (_Float16)acc[i][j];
            else           C[(size_t)row * N + col] = acc[i][j];
        }
    }
}

// ---------------------------------------------------------------------------
// Kernel C (mega): 248 blocks x 512 threads, all co-resident (1 block/CU,
// 248 <= 256 -> spin protocol deadlock-free by construction).
//   blocks 0..7   : GRU — exact r5/r6 hot loop, plus PROGRESS publishes at
//                   st=104/204/274 and final 300 (each: vmcnt drain ->
//                   barrier -> RELEASE store of st; ~3us apiece, r7-measured)
//                   so consumer waves overlap the gru instead of all firing
//                   at the end (r10: exposed tail ~85us).
//   blocks 8..87  : u16 GEMM tile first, then RELEASE-add to flag 8.
//   blocks 8..247 : consumer for ONE (batch=id/30, tc=id%30) chunk. Waits
//                   use fetch_add(0) RMW polls — executed at MALL, never
//                   stale (RELAXED LOADS can spin on a stale XCD-L2 copy of
//                   the flag line; suspected cause of r8/r10's late wakes) —
//                   then one ACQUIRE RMW as the fence. Chunk tc unlocks at
//                   flags[grp] >= (tc+1)*10.
// CRITICAL (gru): all loops fully unrolled so wf[] indices are compile-time
// constants (rule #20).
// ---------------------------------------------------------------------------
__global__ __launch_bounds__(512, 1) void gru_mega(
    const float* __restrict__ gi, const unsigned* __restrict__ wd,
    const float* __restrict__ h0, const float* __restrict__ bhh,
    float* __restrict__ outs, float* __restrict__ hid,
    const float* __restrict__ memory, const float* __restrict__ Um,
    _Float16* __restrict__ u16, const float* __restrict__ W,
    const float* __restrict__ vv, float* __restrict__ attn,
    int* flags, int full) {
    __shared__ __align__(16) _Float16 hbuf[2][256];
    __shared__ float Xs[32][65];
    __shared__ float Ws2[32][65];
    __shared__ unsigned uS[160 * 129];            // 82560B
    __shared__ __align__(16) float oL[10][260];   // outputs rows (padded)
    __shared__ float wLf[10][256];
    __shared__ float vL[256], scP[2][160], sc[160], red[2];

    const int tid = threadIdx.x;

    if (blockIdx.x >= 8) {
        int id = blockIdx.x - 8;                 // 0..239
        // ---------------- u16 GEMM tile (first 80 blocks) ----------------
        if (id < 80) {
            const int n0 = (id & 3) * 64, m0 = (id >> 2) * 64;
            const int tx = tid & 15, ty = (tid & 255) >> 4;
            float acc[4][4] = {};
            for (int k0 = 0; k0 < 256; k0 += 32) {
                if (tid < 256) {
#pragma unroll
                    for (int i = 0; i < 8; ++i) {
                        int e = tid + i * 256;
                        int kk = e & 31, m = e >> 5;
                        Xs[kk][m] = memory[(size_t)(m0 + m) * 256 + k0 + kk];
                        Ws2[kk][m] = Um[(size_t)(n0 + m) * 256 + k0 + kk];
                    }
                }
                __syncthreads();
                if (tid < 256) {
#pragma unroll
                    for (int kk = 0; kk < 32; ++kk) {
                        float a[4], b[4];
#pragma unroll
                        for (int i = 0; i < 4; ++i) a[i] = Xs[kk][ty * 4 + i];
#pragma unroll
                        for (int j = 0; j < 4; ++j) b[j] = Ws2[kk][tx * 4 + j];
#pragma unroll
                        for (int i = 0; i < 4; ++i)
#pragma unroll
                            for (int j = 0; j < 4; ++j) acc[i][j] += a[i] * b[j];
                    }
                }
                __syncthreads();
            }
            if (tid < 256) {
#pragma unroll
                for (int i = 0; i < 4; ++i)
#pragma unroll
                    for (int j = 0; j < 4; ++j)
                        u16[(size_t)(m0 + ty * 4 + i) * 256 + n0 + tx * 4 + j] =
                            (_Float16)acc[i][j];
            }
            if (!full) return;                   // fallback: u16 only
            __syncthreads();                     // drains all waves' stores
            if (tid == 0)
                __hip_atomic_fetch_add(&flags[FLAG(8)], 1, __ATOMIC_RELEASE,
                                       __HIP_MEMORY_SCOPE_AGENT);
        }
        if (!full) return;

        // ---------------- attention consumer (one chunk) -----------------
        const int grp = id / 30;                 // batch 0..7
        const int tc = id % 30;                  // t-chunk 0..29
        // wait all 80 u16 tiles (fresh RMW polls + one ACQUIRE fence)
        if (tid == 0) {
            while (flag_rmw_relaxed(&flags[FLAG(8)]) < 80)
                __builtin_amdgcn_s_sleep(64);
            flag_fence_acquire(&flags[FLAG(8)]);
        }
        __syncthreads();
        // stage uS for this batch (coalesced; padded rows -> conflict-free)
        const unsigned* ug = (const unsigned*)(u16 + (size_t)grp * 160 * 256);
        for (int i = tid; i < 20480; i += 512)
            uS[(i >> 7) * 129 + (i & 127)] = ug[i];
        if (tid < 256) vL[tid] = vv[tid];
        __syncthreads();

        // wait until gru batch grp has produced rows 0..tc*10+9
        const int need = tc * 10 + 10;
        if (tid == 0) {
            while (flag_rmw_relaxed(&flags[FLAG(grp)]) < need)
                __builtin_amdgcn_s_sleep(127);   // ~3.4us between polls
            flag_fence_acquire(&flags[FLAG(grp)]);
        }
        __syncthreads();
        // stage the 10 outputs rows
        for (int i = tid; i < 2560; i += 512) {
            int ti = i >> 8, k = i & 255;
            oL[ti][k] = outs[((size_t)grp * 300 + tc * 10 + ti) * 256 + k];
        }
        __syncthreads();
        // w = rows @ W^T; 512 threads: col c = tid&255, row-group rh = tid>>8
        {
            const int c = tid & 255, rh = tid >> 8;   // rh*5 + 0..4
            float a0 = 0, a1 = 0, a2 = 0, a3 = 0, a4 = 0;
            const float* wr = W + (size_t)c * 256;
            const int r0 = rh * 5;
            for (int k4 = 0; k4 < 256; k4 += 4) {
                float4 wq = *(const float4*)(wr + k4);
#define WROW(ACC, TI)                                                     \
                {                                                         \
                    float4 oq = *(const float4*)(&oL[TI][k4]);            \
                    ACC += wq.x * oq.x + wq.y * oq.y +                    \
                           wq.z * oq.z + wq.w * oq.w;                     \
                }
                WROW(a0, r0 + 0) WROW(a1, r0 + 1) WROW(a2, r0 + 2)
                WROW(a3, r0 + 3) WROW(a4, r0 + 4)
#undef WROW
            }
            wLf[r0 + 0][c] = a0; wLf[r0 + 1][c] = a1; wLf[r0 + 2][c] = a2;
            wLf[r0 + 3][c] = a3; wLf[r0 + 4][c] = a4;
        }
        __syncthreads();
        // scores + softmax; e2-split: 320 workers = 160 x's x 2 k-halves
        for (int ti = 0; ti < 10; ++ti) {
            if (tid < 320) {
                const int x = (tid < 160) ? tid : tid - 160;
                const int half = (tid >= 160) ? 1 : 0;
                const unsigned* ur = uS + x * 129 + half * 64;
                const float* wl = wLf[ti] + half * 128;
                const float* vl = vL + half * 128;
                float acc2 = 0.0f;
#pragma unroll 8
                for (int e2 = 0; e2 < 64; ++e2) {
                    union { unsigned uu2; _Float16 hh[2]; } cv;
                    cv.uu2 = ur[e2];
                    int ee = e2 * 2;
                    acc2 += vl[ee] * ftanh(wl[ee] + (float)cv.hh[0]);
                    acc2 += vl[ee + 1] * ftanh(wl[ee + 1] + (float)cv.hh[1]);
                }
                scP[half][x] = acc2;
            }
            __syncthreads();
            if (tid < 160) sc[tid] = scP[0][tid] + scP[1][tid];
            __syncthreads();
            if (tid < 64) {
                float m = -3.0e38f;
                for (int i = tid; i < 160; i += 64) m = fmaxf(m, sc[i]);
#pragma unroll
                for (int o = 32; o; o >>= 1) m = fmaxf(m, __shfl_xor(m, o));
                if (tid == 0) red[0] = m;
            }
            __syncthreads();
            float ee = 0.0f;
            if (tid < 160) {
                ee = fexp2((sc[tid] - red[0]) * 1.4426950408889634f);
                sc[tid] = ee;
            }
            __syncthreads();
            if (tid < 64) {
                float s = 0.0f;
                for (int i = tid; i < 160; i += 64) s += sc[i];
#pragma unroll
                for (int o = 32; o; o >>= 1) s += __shfl_xor(s, o);
                if (tid == 0) red[1] = s;
            }
            __syncthreads();
            if (tid < 160)
                attn[(size_t)(grp * 300 + tc * 10 + ti) * 160 + tid] =
                    ee * frcp(red[1]);
            __syncthreads();
        }
        return;
    }

    // -------------------------- GRU path (exact r5/r6 hot loop) ----------
    const int b = blockIdx.x;
    const int t = tid;
    const int w = t >> 6, l = t & 63;
    const int grp = l >> 4;
    const int sel = l & 7;
    const int hi = (l >> 3) & 1;
    const int m2s = sel >> 2, rsel = sel & 3;
    const int e = 32 * w + 16 * m2s + 4 * grp + rsel;

    f16x8 wf[48];
#pragma unroll
    for (int fi = 0; fi < 48; ++fi) {
        union { unsigned u[4]; f16x8 v; } cv;
#pragma unroll
        for (int j = 0; j < 4; ++j) cv.u[j] = wd[(fi * 4 + j) * 512 + t];
        wf[fi] = cv.v;
    }

    float h = h0[b * 256 + e];
    float bn = bhh[512 + e];
    if (!hi) hbuf[0][e] = (_Float16)h;
    const float* gp = gi + b * 768;
    float* op = outs + (size_t)b * 76800 + e;

    float gr = gp[e], gz = gp[e + 256], gn = gp[e + 512];
    __syncthreads();

    for (int st = 0; st < 300; ++st) {
        // Progress publish (uniform branch, r7-proven pattern; ~3us each):
        // rows 0..st-1 are complete here. Placed BEFORE the prefetch issue
        // so vmcnt(0) waits only old outs stores.
        if (full && (st == 104 || st == 204 || st == 274)) {
            asm volatile("s_waitcnt vmcnt(0)" ::: "memory");
            __syncthreads();
            if (t == 0)
                __hip_atomic_store(&flags[FLAG(b)], st, __ATOMIC_RELEASE,
                                   __HIP_MEMORY_SCOPE_AGENT);
        }
        int stn = (st < 299) ? st + 1 : st;
        const float* g = gp + (size_t)stn * 6144;
        float grn = g[e], gzn = g[e + 256], gnn = g[e + 512];

        const _Float16* hb = hbuf[st & 1];
        f16x8 hv0 = *(const f16x8*)(hb + 0 * 32 + 8 * grp);
        f16x8 hv1 = *(const f16x8*)(hb + 1 * 32 + 8 * grp);
        f16x8 hv2 = *(const f16x8*)(hb + 2 * 32 + 8 * grp);
        f16x8 hv3 = *(const f16x8*)(hb + 3 * 32 + 8 * grp);
        f16x8 hv4 = *(const f16x8*)(hb + 4 * 32 + 8 * grp);
        f16x8 hv5 = *(const f16x8*)(hb + 5 * 32 + 8 * grp);
        f16x8 hv6 = *(const f16x8*)(hb + 6 * 32 + 8 * grp);
        f16x8 hv7 = *(const f16x8*)(hb + 7 * 32 + 8 * grp);

        f32x4 aR0 = {0.f, 0.f, 0.f, 0.f}, aR1 = {0.f, 0.f, 0.f, 0.f};
        f32x4 aZ0 = {0.f, 0.f, 0.f, 0.f}, aZ1 = {0.f, 0.f, 0.f, 0.f};
        f32x4 aN0 = {0.f, 0.f, 0.f, 0.f}, aN1 = {0.f, 0.f, 0.f, 0.f};
#define KSTEP(ks, hv)                                                        \
        aR0 = __builtin_amdgcn_mfma_f32_16x16x32_f16(wf[0 * 8 + ks], hv, aR0, 0, 0, 0); \
        aR1 = __builtin_amdgcn_mfma_f32_16x16x32_f16(wf[1 * 8 + ks], hv, aR1, 0, 0, 0); \
        aZ0 = __builtin_amdgcn_mfma_f32_16x16x32_f16(wf[2 * 8 + ks], hv, aZ0, 0, 0, 0); \
        aZ1 = __builtin_amdgcn_mfma_f32_16x16x32_f16(wf[3 * 8 + ks], hv, aZ1, 0, 0, 0); \
        aN0 = __builtin_amdgcn_mfma_f32_16x16x32_f16(wf[4 * 8 + ks], hv, aN0, 0, 0, 0); \
        aN1 = __builtin_amdgcn_mfma_f32_16x16x32_f16(wf[5 * 8 + ks], hv, aN1, 0, 0, 0);
        KSTEP(0, hv0) KSTEP(1, hv1) KSTEP(2, hv2) KSTEP(3, hv3)
        KSTEP(4, hv4) KSTEP(5, hv5) KSTEP(6, hv6) KSTEP(7, hv7)
#undef KSTEP

        f32x4 vR = m2s ? aR1 : aR0;
        f32x4 vZ = m2s ? aZ1 : aZ0;
        f32x4 vN = m2s ? aN1 : aN0;
        float sr = pick4(vR, rsel);
        float sz = pick4(vZ, rsel);
        float sn = pick4(vN, rsel);

        float r = fsig(gr + sr);
        float z = fsig(gz + sz);
        float n = ftanh(gn + r * (sn + bn));
        h = n + z * (h - n);

        gr = grn; gz = gzn; gn = gnn;

        if (hi)
            op[st * 256] = h;
        else
            hbuf[(st + 1) & 1][e] = (_Float16)h;
        asm volatile("s_waitcnt lgkmcnt(0)\n\ts_barrier" ::: "memory");
    }
    if (!hi) hid[b * 256 + e] = h;
    if (full) {
        // Final publish: drain stores, rendezvous, RELEASE store st=300.
        asm volatile("s_waitcnt vmcnt(0)" ::: "memory");
        __syncthreads();
        if (t == 0)
            __hip_atomic_store(&flags[FLAG(b)], 300, __ATOMIC_RELEASE,
                               __HIP_MEMORY_SCOPE_AGENT);
    }
}

// ---------------------------------------------------------------------------
// Kernel D (FALLBACK only): r9 fused w-GEMM + scores + softmax.
// ---------------------------------------------------------------------------
__global__ __launch_bounds__(256) void wattn_kernel(
    const _Float16* __restrict__ u16, const float* __restrict__ outs,
    const float* __restrict__ W, const float* __restrict__ vv,
    float* __restrict__ attn) {
    const int tc = blockIdx.x, b = blockIdx.y;
    const int tid = threadIdx.x;
    __shared__ unsigned uS[160 * 129];
    __shared__ __align__(16) float oL[10][260];
    __shared__ float wLf[10][256];
    __shared__ float vL[256], sc[160], red[2];

    const unsigned* ug = (const unsigned*)(u16 + (size_t)b * 160 * 256);
    for (int i = tid; i < 20480; i += 256)
        uS[(i >> 7) * 129 + (i & 127)] = ug[i];
    vL[tid] = vv[tid];
    for (int i = tid; i < 2560; i += 256) {
        int ti = i >> 8, k = i & 255;
        oL[ti][k] = outs[((size_t)b * 300 + tc * 10 + ti) * 256 + k];
    }
    __syncthreads();
    {
        float a0 = 0, a1 = 0, a2 = 0, a3 = 0, a4 = 0;
        float a5 = 0, a6 = 0, a7 = 0, a8 = 0, a9 = 0;
        for (int k4 = 0; k4 < 256; k4 += 4) {
            float4 wq = *(const float4*)(W + (size_t)tid * 256 + k4);
#define WROW(ACC, TI)                                                     \
            {                                                             \
                float4 oq = *(const float4*)(&oL[TI][k4]);                \
                ACC += wq.x * oq.x + wq.y * oq.y +                        \
                       wq.z * oq.z + wq.w * oq.w;                        \
            }
            WROW(a0, 0) WROW(a1, 1) WROW(a2, 2) WROW(a3, 3) WROW(a4, 4)
            WROW(a5, 5) WROW(a6, 6) WROW(a7, 7) WROW(a8, 8) WROW(a9, 9)
#undef WROW
        }
        wLf[0][tid] = a0; wLf[1][tid] = a1; wLf[2][tid] = a2;
        wLf[3][tid] = a3; wLf[4][tid] = a4; wLf[5][tid] = a5;
        wLf[6][tid] = a6; wLf[7][tid] = a7; wLf[8][tid] = a8;
        wLf[9][tid] = a9;
    }
    __syncthreads();
    for (int ti = 0; ti < 10; ++ti) {
        int t = tc * 10 + ti;
        float acc2 = 0.0f;
        if (tid < 160) {
            const unsigned* ur = uS + tid * 129;
            const float* wl = wLf[ti];
#pragma unroll 8
            for (int e2 = 0; e2 < 128; ++e2) {
                union { unsigned uu2; _Float16 hh[2]; } cv;
                cv.uu2 = ur[e2];
                int ee = e2 * 2;
                acc2 += vL[ee] * ftanh(wl[ee] + (float)cv.hh[0]);
                acc2 += vL[ee + 1] * ftanh(wl[ee + 1] + (float)cv.hh[1]);
            }
            sc[tid] = acc2;
        }
        __syncthreads();
        if (tid < 64) {
            float m = -3.0e38f;
            for (int i = tid; i < 160; i += 64) m = fmaxf(m, sc[i]);
#pragma unroll
            for (int o = 32; o; o >>= 1) m = fmaxf(m, __shfl_xor(m, o));
            if (tid == 0) red[0] = m;
        }
        __syncthreads();
        float ee = 0.0f;
        if (tid < 160) {
            ee = fexp2((acc2 - red[0]) * 1.4426950408889634f);
            sc[tid] = ee;
        }
        __syncthreads();
        if (tid < 64) {
            float s = 0.0f;
            for (int i = tid; i < 160; i += 64) s += sc[i];
#pragma unroll
            for (int o = 32; o; o >>= 1) s += __shfl_xor(s, o);
            if (tid == 0) red[1] = s;
        }
        __syncthreads();
        if (tid < 160)
            attn[(size_t)(b * 300 + t) * 160 + tid] = ee * frcp(red[1]);
        __syncthreads();
    }
}

// ---------------------------------------------------------------------------
// ws layout (bytes):
//   [0, 7372800)        gi f32 [(t*8+b)*768 + col]
//   [7372800, 7766016)  wd u32 mfma A-frags [i*512+t]
//   [7766016, 8421376)  u16 f16 [b*160+x][256]     (full path)
//   [8421376, 8422528)  flags, 128B-padded: prog[8] + u16done (full path)
//   fallback (small ws): u16 at ws+0 after gru (aliases dead gi)
// ---------------------------------------------------------------------------
extern "C" void kernel_launch(void* const* d_in, const int* in_sizes, int n_in,
                              void* d_out, int out_size, void* d_ws, size_t ws_size,
                              hipStream_t stream) {
    const float* inputs = (const float*)d_in[0];
    const float* memory = (const float*)d_in[1];
    const float* h0 = (const float*)d_in[2];
    const float* Wih = (const float*)d_in[3];
    const float* Whh = (const float*)d_in[4];
    const float* bih = (const float*)d_in[5];
    const float* bhh = (const float*)d_in[6];
    const float* Wm = (const float*)d_in[7];
    const float* Um = (const float*)d_in[8];
    const float* vv = (const float*)d_in[9];

    float* out = (float*)d_out;
    float* out_attn = out;              // 384000
    float* out_outputs = out + 384000;  // 614400
    float* out_hidden = out + 998400;   // 2048

    char* ws = (char*)d_ws;
    float* gi = (float*)ws;
    unsigned* wd = (unsigned*)(ws + 7372800);

    const size_t U16_OFF = 7766016, FLAG_OFF = 8421376;
    const bool full = ws_size >= FLAG_OFF + 1152;
    _Float16* u16 = full ? (_Float16*)(ws + U16_OFF) : (_Float16*)ws;
    int* flags = (int*)(ws + FLAG_OFF);

    // Phase 1: weight repack + gi GEMM + flag zeroing (one launch).
    phase1_kernel<<<840, 256, 0, stream>>>(Whh, wd, inputs, Wih, gi, bih, bhh,
                                           flags, full ? 1 : 0);
    if (full) {
        // Phase 2: GRU + u16 GEMM + progressively-overlapped w/attention.
        gru_mega<<<248, 512, 0, stream>>>(gi, wd, h0, bhh, out_outputs,
                                          out_hidden, memory, Um, u16, Wm, vv,
                                          out_attn, flags, 1);
    } else {
        // Fallback: serial r9-style pipeline.
        gru_mega<<<8, 512, 0, stream>>>(gi, wd, h0, bhh, out_outputs,
                                        out_hidden, memory, Um, u16, Wm, vv,
                                        out_attn, flags, 0);
        gemm_kernel<<<dim3(4, 20), 256, 0, stream>>>(memory, Um, nullptr, u16,
                                                     1280, 256, 256, 2);
        wattn_kernel<<<dim3(30, 8), 256, 0, stream>>>(u16, out_outputs, Wm, vv,
                                                      out_attn);
    }
}

// Round 12
// 449.508 us; speedup vs baseline: 1.0858x; 1.0858x over previous
//
#include <hip/hip_runtime.h>

// Problem constants
// N=8, T_y=300, T_x=160, E=256, E/2=128, 3E=768
// d_out: [attn 8*300*160 = 384000][outputs 8*300*256 = 614400][hidden 2048]

typedef _Float16 f16x2 __attribute__((ext_vector_type(2)));
typedef _Float16 f16x8 __attribute__((ext_vector_type(8)));
typedef float f32x4 __attribute__((ext_vector_type(4)));

__device__ __forceinline__ float fexp2(float x) { return __builtin_amdgcn_exp2f(x); }
__device__ __forceinline__ float frcp(float x) { return __builtin_amdgcn_rcpf(x); }
__device__ __forceinline__ float fsig(float x) {
    return frcp(1.0f + fexp2(x * -1.4426950408889634f));
}
__device__ __forceinline__ float ftanh(float x) {
    return 1.0f - 2.0f * frcp(1.0f + fexp2(x * 2.8853900817779268f));
}

// select component s (0..3) of a f32x4 with runtime s — pure cndmask tree
// (rule #20: no runtime array indexing).
__device__ __forceinline__ float pick4(f32x4 v, int s) {
    float ab = (s & 1) ? v[1] : v[0];
    float cd = (s & 1) ? v[3] : v[2];
    return (s & 2) ? cd : ab;
}

// Flags live 128B apart (one per cache line).
#define FLAG(i) ((i) * 32)

// ---------------------------------------------------------------------------
// Kernel 1 (phase 1): blocks 0..383 repack Whh into MFMA A-fragment order;
// blocks 384..839 run the gi GEMM (bias-folded, scattered). Block 0 zeroes
// the padded flags. Layout verified r2+ (absmax 0.0039).
// ---------------------------------------------------------------------------
__global__ __launch_bounds__(256) void phase1_kernel(
    const float* __restrict__ Whh, unsigned* __restrict__ wd,
    const float* __restrict__ inputs, const float* __restrict__ Wih,
    float* __restrict__ gi, const float* __restrict__ bih,
    const float* __restrict__ bhh, int* flags, int full) {
    if (full && blockIdx.x == 0 && threadIdx.x < 9)
        flags[FLAG(threadIdx.x)] = 0;
    if (blockIdx.x < 384) {
        int gid = blockIdx.x * 256 + threadIdx.x;   // 0..98303 = 192*512
        int i = gid >> 9, t = gid & 511;
        int fi = i >> 2, j = i & 3;
        int g = fi >> 4, m2 = (fi >> 3) & 1, ks = fi & 7;
        int w = t >> 6, l = t & 63;
        int row = 256 * g + 32 * w + 16 * m2 + (l & 15);
        int k = 32 * ks + 8 * (l >> 4) + 2 * j;
        union { unsigned u; f16x2 h; } cv;
        cv.h[0] = (_Float16)Whh[(size_t)row * 256 + k];
        cv.h[1] = (_Float16)Whh[(size_t)row * 256 + k + 1];
        wd[i * 512 + t] = cv.u;
        return;
    }
    int id = blockIdx.x - 384;                   // 0..455 = 12 x 38
    const int n0 = (id % 12) * 64, m0 = (id / 12) * 64;
    __shared__ float Xs[32][65];
    __shared__ float Ws2[32][65];
    const int tid = threadIdx.x;
    const int tx = tid & 15, ty = tid >> 4;
    const int M = 2400, K = 128;
    float acc[4][4] = {};
    for (int k0 = 0; k0 < K; k0 += 32) {
#pragma unroll
        for (int i = 0; i < 8; ++i) {
            int e = tid + i * 256;
            int kk = e & 31, m = e >> 5;
            int row = m0 + m;
            Xs[kk][m] = (row < M) ? inputs[(size_t)row * K + k0 + kk] : 0.0f;
            Ws2[kk][m] = Wih[(size_t)(n0 + m) * K + k0 + kk];
        }
        __syncthreads();
#pragma unroll
        for (int kk = 0; kk < 32; ++kk) {
            float a[4], b[4];
#pragma unroll
            for (int i = 0; i < 4; ++i) a[i] = Xs[kk][ty * 4 + i];
#pragma unroll
            for (int j = 0; j < 4; ++j) b[j] = Ws2[kk][tx * 4 + j];
#pragma unroll
            for (int i = 0; i < 4; ++i)
#pragma unroll
                for (int j = 0; j < 4; ++j) acc[i][j] += a[i] * b[j];
        }
        __syncthreads();
    }
#pragma unroll
    for (int i = 0; i < 4; ++i) {
        int row = m0 + ty * 4 + i;
        if (row >= M) continue;
        int b = row / 300;
        int t = row - b * 300;
#pragma unroll
        for (int j = 0; j < 4; ++j) {
            int col = n0 + tx * 4 + j;
            float val = acc[i][j] + ((col < 512) ? (bih[col] + bhh[col]) : bih[col]);
            gi[(size_t)(t * 8 + b) * 768 + col] = val;
        }
    }
}

// ---------------------------------------------------------------------------
// Kernel B (FALLBACK only): generic f32 tiled GEMM, mode 2 writes f16.
// ---------------------------------------------------------------------------
__global__ __launch_bounds__(256) void gemm_kernel(
    const float* __restrict__ X, const float* __restrict__ Wt,
    float* __restrict__ C, _Float16* __restrict__ C16,
    int M, int N, int K, int mode) {
    __shared__ float Xs[32][65];
    __shared__ float Ws2[32][65];
    const int n0 = blockIdx.x * 64, m0 = blockIdx.y * 64;
    const int tid = threadIdx.x;
    const int tx = tid & 15, ty = tid >> 4;
    float acc[4][4] = {};
    for (int k0 = 0; k0 < K; k0 += 32) {
#pragma unroll
        for (int i = 0; i < 8; ++i) {
            int e = tid + i * 256;
            int kk = e & 31, m = e >> 5;
            int row = m0 + m;
            Xs[kk][m] = (row < M) ? X[(size_t)row * K + k0 + kk] : 0.0f;
            Ws2[kk][m] = Wt[(size_t)(n0 + m) * K + k0 + kk];
        }
        __syncthreads();
#pragma unroll
        for (int kk = 0; kk < 32; ++kk) {
            float a[4], b[4];
#pragma unroll
            for (int i = 0; i < 4; ++i) a[i] = Xs[kk][ty * 4 + i];
#pragma unroll
            for (int j = 0; j < 4; ++j) b[j] = Ws2[kk][tx * 4 + j];
#pragma unroll
            for (int i = 0; i < 4; ++i)
#pragma unroll
                for (int j = 0; j < 4; ++j) acc[i][j] += a[i] * b[j];
        }
        __syncthreads();
    }
#pragma unroll
    for (int i = 0; i < 4; ++i) {
        int row = m0 + ty * 4 + i;
        if (row >= M) continue;
#pragma unroll
        for (int j = 0; j < 4; ++j) {
            int col = n0 + tx * 4 + j;
            if (mode == 2) C16[(size_t)row * N + col] = (_Float16)acc[i][j];
            else           C[(size_t)row * N + col] = acc[i][j];
        }
    }
}

// ---------------------------------------------------------------------------
// Kernel C (mega): 248 blocks x 512 threads, all co-resident (1 block/CU,
// 248 <= 256 -> spin protocol deadlock-free by construction).
//   blocks 0..7   : GRU — exact r5/r6 hot loop, ZERO in-loop sync, ONE
//                   publish at the end. (r11 lesson: progressive publishes
//                   + consumer activity during the gru pollute L2 under a
//                   latency-sensitive loop; mega 373->395. Reverted.)
//   blocks 8..87  : u16 GEMM tile first, then RELEASE-add to flag 8.
//   blocks 8..247 : consumer for ONE (batch=id/30, tc=id%30) chunk. r10
//                   polling (RELAXED loads + one ACQUIRE confirm; RMW polls
//                   regressed, r11). Tail restructured this round:
//                   ti-PAIRED scores (shared u16 loads, 4 independent acc
//                   chains/thread) + paired softmax (2 rows per barrier
//                   set) -> 30 barriers instead of 60.
// CRITICAL (gru): all loops fully unrolled so wf[] indices are compile-time
// constants (rule #20).
// ---------------------------------------------------------------------------
__global__ __launch_bounds__(512, 1) void gru_mega(
    const float* __restrict__ gi, const unsigned* __restrict__ wd,
    const float* __restrict__ h0, const float* __restrict__ bhh,
    float* __restrict__ outs, float* __restrict__ hid,
    const float* __restrict__ memory, const float* __restrict__ Um,
    _Float16* __restrict__ u16, const float* __restrict__ W,
    const float* __restrict__ vv, float* __restrict__ attn,
    int* flags, int full) {
    __shared__ __align__(16) _Float16 hbuf[2][256];
    __shared__ float Xs[32][65];
    __shared__ float Ws2[32][65];
    __shared__ unsigned uS[160 * 129];            // 82560B
    __shared__ __align__(16) float oL[10][260];   // outputs rows (padded)
    __shared__ float wLf[10][256];
    __shared__ float vL[256];
    __shared__ float scP[2][2][160];              // [tiPar][half][x]
    __shared__ float sc2[2][160];                 // [tiPar][x]
    __shared__ float red2[2][2];                  // [tiPar][max,sum]

    const int tid = threadIdx.x;

    if (blockIdx.x >= 8) {
        int id = blockIdx.x - 8;                 // 0..239
        // ---------------- u16 GEMM tile (first 80 blocks) ----------------
        if (id < 80) {
            const int n0 = (id & 3) * 64, m0 = (id >> 2) * 64;
            const int tx = tid & 15, ty = (tid & 255) >> 4;
            float acc[4][4] = {};
            for (int k0 = 0; k0 < 256; k0 += 32) {
                if (tid < 256) {
#pragma unroll
                    for (int i = 0; i < 8; ++i) {
                        int e = tid + i * 256;
                        int kk = e & 31, m = e >> 5;
                        Xs[kk][m] = memory[(size_t)(m0 + m) * 256 + k0 + kk];
                        Ws2[kk][m] = Um[(size_t)(n0 + m) * 256 + k0 + kk];
                    }
                }
                __syncthreads();
                if (tid < 256) {
#pragma unroll
                    for (int kk = 0; kk < 32; ++kk) {
                        float a[4], b[4];
#pragma unroll
                        for (int i = 0; i < 4; ++i) a[i] = Xs[kk][ty * 4 + i];
#pragma unroll
                        for (int j = 0; j < 4; ++j) b[j] = Ws2[kk][tx * 4 + j];
#pragma unroll
                        for (int i = 0; i < 4; ++i)
#pragma unroll
                            for (int j = 0; j < 4; ++j) acc[i][j] += a[i] * b[j];
                    }
                }
                __syncthreads();
            }
            if (tid < 256) {
#pragma unroll
                for (int i = 0; i < 4; ++i)
#pragma unroll
                    for (int j = 0; j < 4; ++j)
                        u16[(size_t)(m0 + ty * 4 + i) * 256 + n0 + tx * 4 + j] =
                            (_Float16)acc[i][j];
            }
            if (!full) return;                   // fallback: u16 only
            __syncthreads();                     // drains all waves' stores
            if (tid == 0)
                __hip_atomic_fetch_add(&flags[FLAG(8)], 1, __ATOMIC_RELEASE,
                                       __HIP_MEMORY_SCOPE_AGENT);
        }
        if (!full) return;

        // ---------------- attention consumer (one chunk) -----------------
        const int grp = id / 30;                 // batch 0..7
        const int tc = id % 30;                  // t-chunk 0..29
        // wait all 80 u16 tiles (r10 polling: relaxed + one acquire)
        if (tid == 0) {
            while (__hip_atomic_load(&flags[FLAG(8)], __ATOMIC_RELAXED,
                                     __HIP_MEMORY_SCOPE_AGENT) < 80)
                __builtin_amdgcn_s_sleep(64);
            while (__hip_atomic_load(&flags[FLAG(8)], __ATOMIC_ACQUIRE,
                                     __HIP_MEMORY_SCOPE_AGENT) < 80)
                __builtin_amdgcn_s_sleep(8);
        }
        __syncthreads();
        // stage uS for this batch (coalesced; padded rows -> conflict-free)
        const unsigned* ug = (const unsigned*)(u16 + (size_t)grp * 160 * 256);
        for (int i = tid; i < 20480; i += 512)
            uS[(i >> 7) * 129 + (i & 127)] = ug[i];
        if (tid < 256) vL[tid] = vv[tid];
        __syncthreads();

        // wait gru batch grp complete (single publish at the very end)
        if (tid == 0) {
            while (__hip_atomic_load(&flags[FLAG(grp)], __ATOMIC_RELAXED,
                                     __HIP_MEMORY_SCOPE_AGENT) < 1)
                __builtin_amdgcn_s_sleep(127);
            while (__hip_atomic_load(&flags[FLAG(grp)], __ATOMIC_ACQUIRE,
                                     __HIP_MEMORY_SCOPE_AGENT) < 1)
                __builtin_amdgcn_s_sleep(8);
        }
        __syncthreads();
        // stage the 10 outputs rows
        for (int i = tid; i < 2560; i += 512) {
            int ti = i >> 8, k = i & 255;
            oL[ti][k] = outs[((size_t)grp * 300 + tc * 10 + ti) * 256 + k];
        }
        __syncthreads();
        // w = rows @ W^T; 512 threads: col c = tid&255, row-group rh = tid>>8
        {
            const int c = tid & 255, rh = tid >> 8;   // rh*5 + 0..4
            float a0 = 0, a1 = 0, a2 = 0, a3 = 0, a4 = 0;
            const float* wr = W + (size_t)c * 256;
            const int r0 = rh * 5;
            for (int k4 = 0; k4 < 256; k4 += 4) {
                float4 wq = *(const float4*)(wr + k4);
#define WROW(ACC, TI)                                                     \
                {                                                         \
                    float4 oq = *(const float4*)(&oL[TI][k4]);            \
                    ACC += wq.x * oq.x + wq.y * oq.y +                    \
                           wq.z * oq.z + wq.w * oq.w;                     \
                }
                WROW(a0, r0 + 0) WROW(a1, r0 + 1) WROW(a2, r0 + 2)
                WROW(a3, r0 + 3) WROW(a4, r0 + 4)
#undef WROW
            }
            wLf[r0 + 0][c] = a0; wLf[r0 + 1][c] = a1; wLf[r0 + 2][c] = a2;
            wLf[r0 + 3][c] = a3; wLf[r0 + 4][c] = a4;
        }
        __syncthreads();
        // scores + softmax, ti-PAIRED: 5 passes of 2 rows.
        //  - 320 workers: (x, e-half); each computes BOTH rows' partials
        //    with 4 independent acc chains and SHARED u16/v loads.
        //  - reductions: 128 threads = 2 waves, one row per wave.
        for (int tp = 0; tp < 5; ++tp) {
            const int ti0 = tp * 2;
            if (tid < 320) {
                const int x = (tid < 160) ? tid : tid - 160;
                const int half = (tid >= 160) ? 1 : 0;
                const unsigned* ur = uS + x * 129 + half * 64;
                const float* wl0 = wLf[ti0] + half * 128;
                const float* wl1 = wLf[ti0 + 1] + half * 128;
                const float* vl = vL + half * 128;
                float a0 = 0.f, b0 = 0.f, a1 = 0.f, b1 = 0.f;
#pragma unroll 8
                for (int e2 = 0; e2 < 64; ++e2) {
                    union { unsigned uu2; _Float16 hh[2]; } cv;
                    cv.uu2 = ur[e2];
                    int ee = e2 * 2;
                    float u0 = (float)cv.hh[0], u1 = (float)cv.hh[1];
                    float v0 = vl[ee], v1 = vl[ee + 1];
                    a0 += v0 * ftanh(wl0[ee] + u0);
                    b0 += v1 * ftanh(wl0[ee + 1] + u1);
                    a1 += v0 * ftanh(wl1[ee] + u0);
                    b1 += v1 * ftanh(wl1[ee + 1] + u1);
                }
                scP[0][half][x] = a0 + b0;
                scP[1][half][x] = a1 + b1;
            }
            __syncthreads();
            if (tid < 320) {
                int r = (tid >= 160) ? 1 : 0;
                int x = r ? tid - 160 : tid;
                sc2[r][x] = scP[r][0][x] + scP[r][1][x];
            }
            __syncthreads();
            if (tid < 128) {                     // wave0 row0, wave1 row1
                int r = tid >> 6, lane = tid & 63;
                float m = -3.0e38f;
                for (int i = lane; i < 160; i += 64) m = fmaxf(m, sc2[r][i]);
#pragma unroll
                for (int o = 32; o; o >>= 1) m = fmaxf(m, __shfl_xor(m, o));
                if (lane == 0) red2[r][0] = m;
            }
            __syncthreads();
            if (tid < 320) {
                int r = (tid >= 160) ? 1 : 0;
                int x = r ? tid - 160 : tid;
                sc2[r][x] = fexp2((sc2[r][x] - red2[r][0]) *
                                  1.4426950408889634f);
            }
            __syncthreads();
            if (tid < 128) {
                int r = tid >> 6, lane = tid & 63;
                float s = 0.0f;
                for (int i = lane; i < 160; i += 64) s += sc2[r][i];
#pragma unroll
                for (int o = 32; o; o >>= 1) s += __shfl_xor(s, o);
                if (lane == 0) red2[r][1] = s;
            }
            __syncthreads();
            if (tid < 320) {
                int r = (tid >= 160) ? 1 : 0;
                int x = r ? tid - 160 : tid;
                attn[(size_t)(grp * 300 + tc * 10 + ti0 + r) * 160 + x] =
                    sc2[r][x] * frcp(red2[r][1]);
            }
            __syncthreads();
        }
        return;
    }

    // -------------------------- GRU path (exact r5/r6 hot loop) ----------
    const int b = blockIdx.x;
    const int t = tid;
    const int w = t >> 6, l = t & 63;
    const int grp = l >> 4;
    const int sel = l & 7;
    const int hi = (l >> 3) & 1;
    const int m2s = sel >> 2, rsel = sel & 3;
    const int e = 32 * w + 16 * m2s + 4 * grp + rsel;

    f16x8 wf[48];
#pragma unroll
    for (int fi = 0; fi < 48; ++fi) {
        union { unsigned u[4]; f16x8 v; } cv;
#pragma unroll
        for (int j = 0; j < 4; ++j) cv.u[j] = wd[(fi * 4 + j) * 512 + t];
        wf[fi] = cv.v;
    }

    float h = h0[b * 256 + e];
    float bn = bhh[512 + e];
    if (!hi) hbuf[0][e] = (_Float16)h;
    const float* gp = gi + b * 768;
    float* op = outs + (size_t)b * 76800 + e;

    float gr = gp[e], gz = gp[e + 256], gn = gp[e + 512];
    __syncthreads();

    for (int st = 0; st < 300; ++st) {
        int stn = (st < 299) ? st + 1 : st;
        const float* g = gp + (size_t)stn * 6144;
        float grn = g[e], gzn = g[e + 256], gnn = g[e + 512];

        const _Float16* hb = hbuf[st & 1];
        f16x8 hv0 = *(const f16x8*)(hb + 0 * 32 + 8 * grp);
        f16x8 hv1 = *(const f16x8*)(hb + 1 * 32 + 8 * grp);
        f16x8 hv2 = *(const f16x8*)(hb + 2 * 32 + 8 * grp);
        f16x8 hv3 = *(const f16x8*)(hb + 3 * 32 + 8 * grp);
        f16x8 hv4 = *(const f16x8*)(hb + 4 * 32 + 8 * grp);
        f16x8 hv5 = *(const f16x8*)(hb + 5 * 32 + 8 * grp);
        f16x8 hv6 = *(const f16x8*)(hb + 6 * 32 + 8 * grp);
        f16x8 hv7 = *(const f16x8*)(hb + 7 * 32 + 8 * grp);

        f32x4 aR0 = {0.f, 0.f, 0.f, 0.f}, aR1 = {0.f, 0.f, 0.f, 0.f};
        f32x4 aZ0 = {0.f, 0.f, 0.f, 0.f}, aZ1 = {0.f, 0.f, 0.f, 0.f};
        f32x4 aN0 = {0.f, 0.f, 0.f, 0.f}, aN1 = {0.f, 0.f, 0.f, 0.f};
#define KSTEP(ks, hv)                                                        \
        aR0 = __builtin_amdgcn_mfma_f32_16x16x32_f16(wf[0 * 8 + ks], hv, aR0, 0, 0, 0); \
        aR1 = __builtin_amdgcn_mfma_f32_16x16x32_f16(wf[1 * 8 + ks], hv, aR1, 0, 0, 0); \
        aZ0 = __builtin_amdgcn_mfma_f32_16x16x32_f16(wf[2 * 8 + ks], hv, aZ0, 0, 0, 0); \
        aZ1 = __builtin_amdgcn_mfma_f32_16x16x32_f16(wf[3 * 8 + ks], hv, aZ1, 0, 0, 0); \
        aN0 = __builtin_amdgcn_mfma_f32_16x16x32_f16(wf[4 * 8 + ks], hv, aN0, 0, 0, 0); \
        aN1 = __builtin_amdgcn_mfma_f32_16x16x32_f16(wf[5 * 8 + ks], hv, aN1, 0, 0, 0);
        KSTEP(0, hv0) KSTEP(1, hv1) KSTEP(2, hv2) KSTEP(3, hv3)
        KSTEP(4, hv4) KSTEP(5, hv5) KSTEP(6, hv6) KSTEP(7, hv7)
#undef KSTEP

        f32x4 vR = m2s ? aR1 : aR0;
        f32x4 vZ = m2s ? aZ1 : aZ0;
        f32x4 vN = m2s ? aN1 : aN0;
        float sr = pick4(vR, rsel);
        float sz = pick4(vZ, rsel);
        float sn = pick4(vN, rsel);

        float r = fsig(gr + sr);
        float z = fsig(gz + sz);
        float n = ftanh(gn + r * (sn + bn));
        h = n + z * (h - n);

        gr = grn; gz = gzn; gn = gnn;

        if (hi)
            op[st * 256] = h;
        else
            hbuf[(st + 1) & 1][e] = (_Float16)h;
        asm volatile("s_waitcnt lgkmcnt(0)\n\ts_barrier" ::: "memory");
    }
    if (!hi) hid[b * 256 + e] = h;
    if (full) {
        // ONE publish per block: drain stores, rendezvous, RELEASE store.
        asm volatile("s_waitcnt vmcnt(0)" ::: "memory");
        __syncthreads();
        if (t == 0)
            __hip_atomic_store(&flags[FLAG(b)], 1, __ATOMIC_RELEASE,
                               __HIP_MEMORY_SCOPE_AGENT);
    }
}

// ---------------------------------------------------------------------------
// Kernel D (FALLBACK only): r9 fused w-GEMM + scores + softmax.
// ---------------------------------------------------------------------------
__global__ __launch_bounds__(256) void wattn_kernel(
    const _Float16* __restrict__ u16, const float* __restrict__ outs,
    const float* __restrict__ W, const float* __restrict__ vv,
    float* __restrict__ attn) {
    const int tc = blockIdx.x, b = blockIdx.y;
    const int tid = threadIdx.x;
    __shared__ unsigned uS[160 * 129];
    __shared__ __align__(16) float oL[10][260];
    __shared__ float wLf[10][256];
    __shared__ float vL[256], sc[160], red[2];

    const unsigned* ug = (const unsigned*)(u16 + (size_t)b * 160 * 256);
    for (int i = tid; i < 20480; i += 256)
        uS[(i >> 7) * 129 + (i & 127)] = ug[i];
    vL[tid] = vv[tid];
    for (int i = tid; i < 2560; i += 256) {
        int ti = i >> 8, k = i & 255;
        oL[ti][k] = outs[((size_t)b * 300 + tc * 10 + ti) * 256 + k];
    }
    __syncthreads();
    {
        float a0 = 0, a1 = 0, a2 = 0, a3 = 0, a4 = 0;
        float a5 = 0, a6 = 0, a7 = 0, a8 = 0, a9 = 0;
        for (int k4 = 0; k4 < 256; k4 += 4) {
            float4 wq = *(const float4*)(W + (size_t)tid * 256 + k4);
#define WROW(ACC, TI)                                                     \
            {                                                             \
                float4 oq = *(const float4*)(&oL[TI][k4]);                \
                ACC += wq.x * oq.x + wq.y * oq.y +                        \
                       wq.z * oq.z + wq.w * oq.w;                        \
            }
            WROW(a0, 0) WROW(a1, 1) WROW(a2, 2) WROW(a3, 3) WROW(a4, 4)
            WROW(a5, 5) WROW(a6, 6) WROW(a7, 7) WROW(a8, 8) WROW(a9, 9)
#undef WROW
        }
        wLf[0][tid] = a0; wLf[1][tid] = a1; wLf[2][tid] = a2;
        wLf[3][tid] = a3; wLf[4][tid] = a4; wLf[5][tid] = a5;
        wLf[6][tid] = a6; wLf[7][tid] = a7; wLf[8][tid] = a8;
        wLf[9][tid] = a9;
    }
    __syncthreads();
    for (int ti = 0; ti < 10; ++ti) {
        int t = tc * 10 + ti;
        float acc2 = 0.0f;
        if (tid < 160) {
            const unsigned* ur = uS + tid * 129;
            const float* wl = wLf[ti];
#pragma unroll 8
            for (int e2 = 0; e2 < 128; ++e2) {
                union { unsigned uu2; _Float16 hh[2]; } cv;
                cv.uu2 = ur[e2];
                int ee = e2 * 2;
                acc2 += vL[ee] * ftanh(wl[ee] + (float)cv.hh[0]);
                acc2 += vL[ee + 1] * ftanh(wl[ee + 1] + (float)cv.hh[1]);
            }
            sc[tid] = acc2;
        }
        __syncthreads();
        if (tid < 64) {
            float m = -3.0e38f;
            for (int i = tid; i < 160; i += 64) m = fmaxf(m, sc[i]);
#pragma unroll
            for (int o = 32; o; o >>= 1) m = fmaxf(m, __shfl_xor(m, o));
            if (tid == 0) red[0] = m;
        }
        __syncthreads();
        float ee = 0.0f;
        if (tid < 160) {
            ee = fexp2((acc2 - red[0]) * 1.4426950408889634f);
            sc[tid] = ee;
        }
        __syncthreads();
        if (tid < 64) {
            float s = 0.0f;
            for (int i = tid; i < 160; i += 64) s += sc[i];
#pragma unroll
            for (int o = 32; o; o >>= 1) s += __shfl_xor(s, o);
            if (tid == 0) red[1] = s;
        }
        __syncthreads();
        if (tid < 160)
            attn[(size_t)(b * 300 + t) * 160 + tid] = ee * frcp(red[1]);
        __syncthreads();
    }
}

// ---------------------------------------------------------------------------
// ws layout (bytes):
//   [0, 7372800)        gi f32 [(t*8+b)*768 + col]
//   [7372800, 7766016)  wd u32 mfma A-frags [i*512+t]
//   [7766016, 8421376)  u16 f16 [b*160+x][256]     (full path)
//   [8421376, 8422528)  flags, 128B-padded: prog[8] + u16done (full path)
//   fallback (small ws): u16 at ws+0 after gru (aliases dead gi)
// ---------------------------------------------------------------------------
extern "C" void kernel_launch(void* const* d_in, const int* in_sizes, int n_in,
                              void* d_out, int out_size, void* d_ws, size_t ws_size,
                              hipStream_t stream) {
    const float* inputs = (const float*)d_in[0];
    const float* memory = (const float*)d_in[1];
    const float* h0 = (const float*)d_in[2];
    const float* Wih = (const float*)d_in[3];
    const float* Whh = (const float*)d_in[4];
    const float* bih = (const float*)d_in[5];
    const float* bhh = (const float*)d_in[6];
    const float* Wm = (const float*)d_in[7];
    const float* Um = (const float*)d_in[8];
    const float* vv = (const float*)d_in[9];

    float* out = (float*)d_out;
    float* out_attn = out;              // 384000
    float* out_outputs = out + 384000;  // 614400
    float* out_hidden = out + 998400;   // 2048

    char* ws = (char*)d_ws;
    float* gi = (float*)ws;
    unsigned* wd = (unsigned*)(ws + 7372800);

    const size_t U16_OFF = 7766016, FLAG_OFF = 8421376;
    const bool full = ws_size >= FLAG_OFF + 1152;
    _Float16* u16 = full ? (_Float16*)(ws + U16_OFF) : (_Float16*)ws;
    int* flags = (int*)(ws + FLAG_OFF);

    // Phase 1: weight repack + gi GEMM + flag zeroing (one launch).
    phase1_kernel<<<840, 256, 0, stream>>>(Whh, wd, inputs, Wih, gi, bih, bhh,
                                           flags, full ? 1 : 0);
    if (full) {
        // Phase 2: GRU + u16 GEMM + tail consumers (r10 protocol, faster tail).
        gru_mega<<<248, 512, 0, stream>>>(gi, wd, h0, bhh, out_outputs,
                                          out_hidden, memory, Um, u16, Wm, vv,
                                          out_attn, flags, 1);
    } else {
        // Fallback: serial r9-style pipeline.
        gru_mega<<<8, 512, 0, stream>>>(gi, wd, h0, bhh, out_outputs,
                                        out_hidden, memory, Um, u16, Wm, vv,
                                        out_attn, flags, 0);
        gemm_kernel<<<dim3(4, 20), 256, 0, stream>>>(memory, Um, nullptr, u16,
                                                     1280, 256, 256, 2);
        wattn_kernel<<<dim3(30, 8), 256, 0, stream>>>(u16, out_outputs, Wm, vv,
                                                      out_attn);
    }
}